// Round 11
// baseline (277.908 us; speedup 1.0000x reference)
//
#include <hip/hip_runtime.h>

#define NN 20000
#define NE 320000

typedef __attribute__((ext_vector_type(8))) short bf16x8;
typedef __attribute__((ext_vector_type(4))) float f32x4;
typedef __attribute__((ext_vector_type(2))) float f32x2;

__device__ __forceinline__ float bf2f(unsigned short u) {
  union { unsigned int i; float f; } v; v.i = ((unsigned int)u) << 16; return v.f;
}
__device__ __forceinline__ unsigned short f2bf(float f) {
  union { float f; unsigned int i; } v; v.f = f;
  unsigned int r = v.i + 0x7FFF + ((v.i >> 16) & 1);
  return (unsigned short)(r >> 16);
}
__device__ __forceinline__ float4 ld_bf4(const unsigned short* p) {
  ushort4 u = *(const ushort4*)p;
  float4 f;
  f.x = bf2f(u.x); f.y = bf2f(u.y); f.z = bf2f(u.z); f.w = bf2f(u.w);
  return f;
}

// 16-lane (DPP row) sum: 4 VALU adds, no LGKM. All 16 lanes end with the total.
__device__ __forceinline__ float rsum16(float v) {
  v += __int_as_float(__builtin_amdgcn_mov_dpp(__float_as_int(v), 0x121, 0xF, 0xF, true));
  v += __int_as_float(__builtin_amdgcn_mov_dpp(__float_as_int(v), 0x122, 0xF, 0xF, true));
  v += __int_as_float(__builtin_amdgcn_mov_dpp(__float_as_int(v), 0x124, 0xF, 0xF, true));
  v += __int_as_float(__builtin_amdgcn_mov_dpp(__float_as_int(v), 0x128, 0xF, 0xF, true));
  return v;
}

// ---- packed fp32 FMA with SGPR-resident coefficient pair (asm verified in round 0) ----
// pk_bl_s: acc.{lo,hi} += w.{lo,hi} * ea.lo ; pk_bh_s: acc.{lo,hi} += w.{lo,hi} * ea.hi
// ea is the single allowed SGPR operand of the VOP3P instruction.
__device__ __forceinline__ void pk_bl_s(f32x2& acc, f32x2 w, f32x2 ea) {
  asm("v_pk_fma_f32 %0, %1, %2, %0 op_sel:[0,0,0] op_sel_hi:[1,0,1]"
      : "+v"(acc) : "v"(w), "s"(ea));
}
__device__ __forceinline__ void pk_bh_s(f32x2& acc, f32x2 w, f32x2 ea) {
  asm("v_pk_fma_f32 %0, %1, %2, %0 op_sel:[0,1,0] op_sel_hi:[1,1,1]"
      : "+v"(acc) : "v"(w), "s"(ea));
}

// ---------------- CSR construction ----------------

__global__ void count_dst(const int* __restrict__ ei, int* __restrict__ counts) {
  int e = blockIdx.x * blockDim.x + threadIdx.x;
  if (e < NE) atomicAdd(&counts[ei[NE + e]], 1);
}

__global__ void scan_local(const int* __restrict__ counts, int* __restrict__ tmp,
                           int* __restrict__ bsum) {
  __shared__ int sh[1024];
  int b = blockIdx.x, t = threadIdx.x, i = b * 1024 + t;
  int v = (i < NN) ? counts[i] : 0;
  sh[t] = v;
  __syncthreads();
  for (int off = 1; off < 1024; off <<= 1) {
    int add = (t >= off) ? sh[t - off] : 0;
    __syncthreads();
    sh[t] += add;
    __syncthreads();
  }
  if (i < NN) tmp[i] = sh[t];
  if (t == 1023) bsum[b] = sh[t];
}

__global__ void scan_bsum(int* __restrict__ bsum, int nb) {
  if (threadIdx.x == 0) {
    int run = 0;
    for (int j = 0; j < nb; ++j) { int v = bsum[j]; bsum[j] = run; run += v; }
  }
}

__global__ void scan_finish(const int* __restrict__ counts, const int* __restrict__ tmp,
                            const int* __restrict__ bsum, int* __restrict__ row_ptr,
                            int* __restrict__ cursor) {
  int i = blockIdx.x * 256 + threadIdx.x;
  if (i == 0) row_ptr[0] = 0;
  if (i < NN) {
    int incl = tmp[i] + bsum[i >> 10];
    row_ptr[i + 1] = incl;
    cursor[i] = incl - counts[i];
  }
}

__global__ void scatter_edges(const int* __restrict__ ei, const float4* __restrict__ eattr4,
                              int* __restrict__ cursor, int* __restrict__ srcs,
                              float4* __restrict__ ea_r) {
  int e = blockIdx.x * blockDim.x + threadIdx.x;
  if (e < NE) {
    int d = ei[NE + e];
    int pos = atomicAdd(&cursor[d], 1);
    srcs[pos] = ei[e];
    float4 a0 = eattr4[(size_t)e * 4 + 0];
    float4 a1 = eattr4[(size_t)e * 4 + 1];
    float4 a2 = eattr4[(size_t)e * 4 + 2];
    float4 a3 = eattr4[(size_t)e * 4 + 3];
    ea_r[(size_t)pos * 4 + 0] = a0;
    ea_r[(size_t)pos * 4 + 1] = a1;
    ea_r[(size_t)pos * 4 + 2] = a2;
    ea_r[(size_t)pos * 4 + 3] = a3;
  }
}

// ---------------- split-bf16 conversion ----------------

__global__ void split_bf16(const float* __restrict__ src, unsigned short* __restrict__ hi,
                           unsigned short* __restrict__ lo, int n) {
  int i = blockIdx.x * 256 + threadIdx.x;
  if (i < n) {
    float v = src[i];
    unsigned short h = f2bf(v);
    hi[i] = h;
    lo[i] = f2bf(v - bf2f(h));
  }
}

__global__ void cat_split_T(const float* __restrict__ W1, const float* __restrict__ W2,
                            unsigned short* __restrict__ hi, unsigned short* __restrict__ lo,
                            int N0, int K, int total) {
  int i = blockIdx.x * 256 + threadIdx.x;
  if (i < total) {
    int n = i / K, k = i - n * K;
    float v = (n < N0) ? W1[k * N0 + n] : W2[k * N0 + n - N0];
    unsigned short h = f2bf(v);
    hi[i] = h;
    lo[i] = f2bf(v - bf2f(h));
  }
}

// ---------------- split-bf16 MFMA GEMM, B-resident-in-LDS ----------------
// WLO=false skips the lo-plane C store (dead for x1/x2: fused kernels read hi only).

template<int K, bool WLO>
__global__ __launch_bounds__(256) void mfma_gemm_B(
    const unsigned short* __restrict__ Ah, const unsigned short* __restrict__ Al,
    const unsigned short* __restrict__ Bth, const unsigned short* __restrict__ Btl,
    unsigned short* __restrict__ Ch, unsigned short* __restrict__ Cl, int M, int N) {
  constexpr int BP = K + 24;
  __shared__ unsigned short Bsh[64 * BP], Bsl[64 * BP];
  int t = threadIdx.x;
  int wv = t >> 6, lane = t & 63;
  int quad = lane >> 4, mrow = lane & 15;
  int m0 = blockIdx.x * 64;
  int n0 = blockIdx.y * 64;

  for (int idx = t; idx < 64 * K / 8; idx += 256) {
    int n = idx / (K / 8), seg = (idx - n * (K / 8)) * 8;
    *(uint4*)(Bsh + n * BP + seg) = *(const uint4*)(Bth + (size_t)(n0 + n) * K + seg);
    *(uint4*)(Bsl + n * BP + seg) = *(const uint4*)(Btl + (size_t)(n0 + n) * K + seg);
  }
  __syncthreads();

  f32x4 acc[4];
#pragma unroll
  for (int i = 0; i < 4; ++i) acc[i] = (f32x4){0.f, 0.f, 0.f, 0.f};

  int arow = m0 + wv * 16 + mrow;
  if (arow >= M) arow = M - 1;
  const unsigned short* ap_h = Ah + (size_t)arow * K + quad * 8;
  const unsigned short* ap_l = Al + (size_t)arow * K + quad * 8;

  for (int ks = 0; ks < K; ks += 32) {
    bf16x8 ah = *(const bf16x8*)(ap_h + ks);
    bf16x8 al = *(const bf16x8*)(ap_l + ks);
#pragma unroll
    for (int nt = 0; nt < 4; ++nt) {
      bf16x8 bh = *(const bf16x8*)(Bsh + (nt * 16 + mrow) * BP + ks + quad * 8);
      bf16x8 bl = *(const bf16x8*)(Bsl + (nt * 16 + mrow) * BP + ks + quad * 8);
      acc[nt] = __builtin_amdgcn_mfma_f32_16x16x32_bf16(ah, bh, acc[nt], 0, 0, 0);
      acc[nt] = __builtin_amdgcn_mfma_f32_16x16x32_bf16(ah, bl, acc[nt], 0, 0, 0);
      acc[nt] = __builtin_amdgcn_mfma_f32_16x16x32_bf16(al, bh, acc[nt], 0, 0, 0);
    }
  }
#pragma unroll
  for (int nt = 0; nt < 4; ++nt)
#pragma unroll
    for (int r = 0; r < 4; ++r) {
      int row = m0 + wv * 16 + quad * 4 + r;
      if (row < M) {
        float f = acc[nt][r];
        unsigned short h = f2bf(f);
        size_t o = (size_t)row * N + n0 + nt * 16 + mrow;
        Ch[o] = h;
        if constexpr (WLO) Cl[o] = f2bf(f - bf2f(h));
      }
    }
}

// ---------------- FUSED layer 1 (round-9 structure; packed-fp32 ea@We) ----------
// One wave per node (1-wave blocks), 2 edges/iter, scalar srcs/ea (s_load path).
// Round-10: ea@We uses v_pk_fma_f32 with the SGPR coefficient pair as the scalar
// operand -> 64 FMA issues per pair instead of 128. Kernel is VALU-throughput-bound
// (60% busy), so instruction reduction is the lever. Round-0's packed failure was
// the latency-bound + VGPR-operand regime; both conditions are gone.
// Width/pipelining FINAL: 4-wide regressed (r3, r6), manual prefetch regressed (r8).

__global__ __launch_bounds__(64, 1) void fused1(
    const int* __restrict__ srcs, const int* __restrict__ row_ptr,
    const float4* __restrict__ ea_r, const unsigned short* __restrict__ xh,
    const float* __restrict__ We, const float* __restrict__ att,
    const float* __restrict__ bias, unsigned short* __restrict__ h_hi,
    unsigned short* __restrict__ h_lo) {
  int lane = threadIdx.x & 63;
  int n = __builtin_amdgcn_readfirstlane(blockIdx.x);
  int col = (lane >> 4) * 64 + (lane & 15) * 4;
  f32x2 welo[16], wehi[16];
#pragma unroll
  for (int k = 0; k < 16; ++k) {
    float4 w4 = *(const float4*)(We + k * 256 + col);
    welo[k] = (f32x2){w4.x, w4.y};
    wehi[k] = (f32x2){w4.z, w4.w};
  }
  float4 at = *(const float4*)(att + col);
  float4 ra = ld_bf4(xh + (size_t)n * 512 + 256 + col);
  int beg = __builtin_amdgcn_readfirstlane(row_ptr[n]);
  int end = __builtin_amdgcn_readfirstlane(row_ptr[n + 1]);
  float den0 = 0.f, den1 = 0.f;
  float4 A0 = {0, 0, 0, 0}, A1 = {0, 0, 0, 0};
  int i = beg;
  for (; i + 2 <= end; i += 2) {
    int s0 = __builtin_amdgcn_readfirstlane(srcs[i]);
    int s1 = __builtin_amdgcn_readfirstlane(srcs[i + 1]);
    float4 xa = ld_bf4(xh + (size_t)s0 * 512 + col);
    float4 xb = ld_bf4(xh + (size_t)s1 * 512 + col);
    const f32x2* e2 = (const f32x2*)(ea_r + (size_t)i * 4);  // 16 SGPR pairs (2 edges)
    f32x2 v0lo = {xa.x + ra.x, xa.y + ra.y}, v0hi = {xa.z + ra.z, xa.w + ra.w};
    f32x2 v1lo = {xb.x + ra.x, xb.y + ra.y}, v1hi = {xb.z + ra.z, xb.w + ra.w};
#pragma unroll
    for (int k = 0; k < 8; ++k) {
      f32x2 e = e2[k];
      pk_bl_s(v0lo, welo[2 * k], e);     pk_bl_s(v0hi, wehi[2 * k], e);
      pk_bh_s(v0lo, welo[2 * k + 1], e); pk_bh_s(v0hi, wehi[2 * k + 1], e);
    }
#pragma unroll
    for (int k = 0; k < 8; ++k) {
      f32x2 e = e2[8 + k];
      pk_bl_s(v1lo, welo[2 * k], e);     pk_bl_s(v1hi, wehi[2 * k], e);
      pk_bh_s(v1lo, welo[2 * k + 1], e); pk_bh_s(v1hi, wehi[2 * k + 1], e);
    }
    float a0 = fmaxf(v0lo.x, 0.2f * v0lo.x), a1 = fmaxf(v0lo.y, 0.2f * v0lo.y);
    float a2 = fmaxf(v0hi.x, 0.2f * v0hi.x), a3 = fmaxf(v0hi.y, 0.2f * v0hi.y);
    float b0 = fmaxf(v1lo.x, 0.2f * v1lo.x), b1 = fmaxf(v1lo.y, 0.2f * v1lo.y);
    float b2 = fmaxf(v1hi.x, 0.2f * v1hi.x), b3 = fmaxf(v1hi.y, 0.2f * v1hi.y);
    float sA = at.x * a0 + at.y * a1 + at.z * a2 + at.w * a3;
    float sB = at.x * b0 + at.y * b1 + at.z * b2 + at.w * b3;
    sA = rsum16(sA);
    sB = rsum16(sB);
    float pA = __expf(sA), pB = __expf(sB);
    den0 += pA; den1 += pB;
    A0.x += pA * xa.x; A0.y += pA * xa.y; A0.z += pA * xa.z; A0.w += pA * xa.w;
    A1.x += pB * xb.x; A1.y += pB * xb.y; A1.z += pB * xb.z; A1.w += pB * xb.w;
  }
  if (i < end) {  // tail edge
    int s0 = __builtin_amdgcn_readfirstlane(srcs[i]);
    float4 xa = ld_bf4(xh + (size_t)s0 * 512 + col);
    const f32x2* e2 = (const f32x2*)(ea_r + (size_t)i * 4);
    f32x2 v0lo = {xa.x + ra.x, xa.y + ra.y}, v0hi = {xa.z + ra.z, xa.w + ra.w};
#pragma unroll
    for (int k = 0; k < 8; ++k) {
      f32x2 e = e2[k];
      pk_bl_s(v0lo, welo[2 * k], e);     pk_bl_s(v0hi, wehi[2 * k], e);
      pk_bh_s(v0lo, welo[2 * k + 1], e); pk_bh_s(v0hi, wehi[2 * k + 1], e);
    }
    float a0 = fmaxf(v0lo.x, 0.2f * v0lo.x), a1 = fmaxf(v0lo.y, 0.2f * v0lo.y);
    float a2 = fmaxf(v0hi.x, 0.2f * v0hi.x), a3 = fmaxf(v0hi.y, 0.2f * v0hi.y);
    float sA = at.x * a0 + at.y * a1 + at.z * a2 + at.w * a3;
    sA = rsum16(sA);
    float pA = __expf(sA);
    den0 += pA;
    A0.x += pA * xa.x; A0.y += pA * xa.y; A0.z += pA * xa.z; A0.w += pA * xa.w;
  }
  float D = den0 + den1;
  float4 A;
  A.x = A0.x + A1.x;
  A.y = A0.y + A1.y;
  A.z = A0.z + A1.z;
  A.w = A0.w + A1.w;
  bool has = end > beg;
  float rd = has ? 1.f / D : 0.f;
  float4 b4 = *(const float4*)(bias + col);
  float4 o;
  o.x = A.x * rd + b4.x;
  o.y = A.y * rd + b4.y;
  o.z = A.z * rd + b4.z;
  o.w = A.w * rd + b4.w;
  o.x = (o.x > 0.f) ? o.x : (__expf(o.x) - 1.f);
  o.y = (o.y > 0.f) ? o.y : (__expf(o.y) - 1.f);
  o.z = (o.z > 0.f) ? o.z : (__expf(o.z) - 1.f);
  o.w = (o.w > 0.f) ? o.w : (__expf(o.w) - 1.f);
  ushort4 oh, ol;
  oh.x = f2bf(o.x); ol.x = f2bf(o.x - bf2f(oh.x));
  oh.y = f2bf(o.y); ol.y = f2bf(o.y - bf2f(oh.y));
  oh.z = f2bf(o.z); ol.z = f2bf(o.z - bf2f(oh.z));
  oh.w = f2bf(o.w); ol.w = f2bf(o.w - bf2f(oh.w));
  *(ushort4*)(h_hi + (size_t)n * 256 + col) = oh;
  *(ushort4*)(h_lo + (size_t)n * 256 + col) = ol;
}

// ---------------- FUSED layer 2 (round-9 winner, byte-identical) ----------
// Whole wave per edge, 1 channel/lane (C=64), 2 edges/iter: srcs[i] readfirstlane'd,
// ea_r wave-uniform -> scalar s_loads, We column in 16 VGPRs with SGPR ea coefficients.

__global__ __launch_bounds__(64, 1) void fused2(
    const int* __restrict__ srcs, const int* __restrict__ row_ptr,
    const float* __restrict__ ea_r, const unsigned short* __restrict__ xh,
    const float* __restrict__ We, const float* __restrict__ att,
    const float* __restrict__ bias, float* __restrict__ out) {
  int lane = threadIdx.x & 63;
  int n = __builtin_amdgcn_readfirstlane(blockIdx.x);
  float wcol[16];
#pragma unroll
  for (int k = 0; k < 16; ++k) wcol[k] = We[k * 64 + lane];
  float at = att[lane];
  float ra = bf2f(xh[(size_t)n * 128 + 64 + lane]);
  int beg = __builtin_amdgcn_readfirstlane(row_ptr[n]);
  int end = __builtin_amdgcn_readfirstlane(row_ptr[n + 1]);
  float den0 = 0.f, den1 = 0.f;
  float A0 = 0.f, A1 = 0.f;
  int i = beg;
  for (; i + 2 <= end; i += 2) {
    int s0 = __builtin_amdgcn_readfirstlane(srcs[i]);
    int s1 = __builtin_amdgcn_readfirstlane(srcs[i + 1]);
    float xa0 = bf2f(xh[(size_t)s0 * 128 + lane]);
    float xa1 = bf2f(xh[(size_t)s1 * 128 + lane]);
    const float* ep = ea_r + (size_t)i * 16;  // 32 scalar floats (edges i, i+1)
    float v0 = xa0 + ra, v1 = xa1 + ra;
#pragma unroll
    for (int k = 0; k < 16; ++k) v0 += ep[k] * wcol[k];
#pragma unroll
    for (int k = 0; k < 16; ++k) v1 += ep[16 + k] * wcol[k];
    v0 = fmaxf(v0, 0.2f * v0);
    v1 = fmaxf(v1, 0.2f * v1);
    float sA = at * v0, sB = at * v1;
    sA = rsum16(sA); sB = rsum16(sB);
    sA += __shfl_xor(sA, 16); sB += __shfl_xor(sB, 16);
    sA += __shfl_xor(sA, 32); sB += __shfl_xor(sB, 32);
    float pA = __expf(sA), pB = __expf(sB);
    den0 += pA; den1 += pB;
    A0 += pA * xa0; A1 += pB * xa1;
  }
  if (i < end) {  // tail edge
    int s0 = __builtin_amdgcn_readfirstlane(srcs[i]);
    float xa0 = bf2f(xh[(size_t)s0 * 128 + lane]);
    const float* ep = ea_r + (size_t)i * 16;
    float v0 = xa0 + ra;
#pragma unroll
    for (int k = 0; k < 16; ++k) v0 += ep[k] * wcol[k];
    v0 = fmaxf(v0, 0.2f * v0);
    float sA = at * v0;
    sA = rsum16(sA);
    sA += __shfl_xor(sA, 16);
    sA += __shfl_xor(sA, 32);
    float pA = __expf(sA);
    den0 += pA;
    A0 += pA * xa0;
  }
  float D = den0 + den1;
  float A = A0 + A1;
  bool has = end > beg;
  float o = (has ? A / D : 0.f) + bias[lane];
  out[(size_t)n * 64 + lane] = o;
}

// ---------------- launch ----------------

extern "C" void kernel_launch(void* const* d_in, const int* in_sizes, int n_in,
                              void* d_out, int out_size, void* d_ws, size_t ws_size,
                              hipStream_t stream) {
  const float* x    = (const float*)d_in[0];
  const int*   ei   = (const int*)  d_in[1];
  const float* eatt = (const float*)d_in[2];
  const float* Wl1  = (const float*)d_in[3];
  const float* Wr1  = (const float*)d_in[4];
  const float* We1  = (const float*)d_in[5];
  const float* att1 = (const float*)d_in[6];
  const float* b1   = (const float*)d_in[7];
  const float* Wl2  = (const float*)d_in[8];
  const float* Wr2  = (const float*)d_in[9];
  const float* We2  = (const float*)d_in[10];
  const float* att2 = (const float*)d_in[11];
  const float* b2   = (const float*)d_in[12];
  float* out = (float*)d_out;

  char* wsb = (char*)d_ws;
  size_t off = 0;
  auto alloc = [&](size_t bytes) {
    char* p = wsb + off;
    off += (bytes + 255) & ~(size_t)255;
    return p;
  };
  int* counts    = (int*)alloc((size_t)NN * 4);
  int* tmp       = (int*)alloc((size_t)NN * 4);
  int* bsum      = (int*)alloc(32 * 4);
  int* row_ptr   = (int*)alloc((size_t)(NN + 1) * 4);
  int* cursor    = (int*)alloc((size_t)NN * 4);
  int* srcs      = (int*)alloc((size_t)NE * 4);
  float4* ea_r   = (float4*)alloc((size_t)NE * 16 * 4);
  unsigned short* x_hi  = (unsigned short*)alloc((size_t)NN * 128 * 2);
  unsigned short* x_lo  = (unsigned short*)alloc((size_t)NN * 128 * 2);
  unsigned short* W1th  = (unsigned short*)alloc((size_t)512 * 128 * 2);
  unsigned short* W1tl  = (unsigned short*)alloc((size_t)512 * 128 * 2);
  unsigned short* W2th  = (unsigned short*)alloc((size_t)128 * 256 * 2);
  unsigned short* W2tl  = (unsigned short*)alloc((size_t)128 * 256 * 2);
  unsigned short* h_hi  = (unsigned short*)alloc((size_t)NN * 256 * 2);
  unsigned short* h_lo  = (unsigned short*)alloc((size_t)NN * 256 * 2);
  unsigned short* x1h   = (unsigned short*)alloc((size_t)NN * 512 * 2);
  unsigned short* x2h   = (unsigned short*)alloc((size_t)NN * 128 * 2);

  // CSR by destination (+ srcs + edge_attr reorder)
  hipMemsetAsync(counts, 0, (size_t)NN * 4, stream);
  count_dst<<<(NE + 255) / 256, 256, 0, stream>>>(ei, counts);
  scan_local<<<(NN + 1023) / 1024, 1024, 0, stream>>>(counts, tmp, bsum);
  scan_bsum<<<1, 64, 0, stream>>>(bsum, (NN + 1023) / 1024);
  scan_finish<<<(NN + 255) / 256, 256, 0, stream>>>(counts, tmp, bsum, row_ptr, cursor);
  scatter_edges<<<(NE + 255) / 256, 256, 0, stream>>>(ei, (const float4*)eatt, cursor,
                                                      srcs, ea_r);

  // split-bf16 conversions (W transposed for the B-resident GEMM)
  split_bf16<<<(NN * 128 + 255) / 256, 256, 0, stream>>>(x, x_hi, x_lo, NN * 128);
  cat_split_T<<<(512 * 128 + 255) / 256, 256, 0, stream>>>(Wl1, Wr1, W1th, W1tl, 256, 128,
                                                           512 * 128);
  cat_split_T<<<(128 * 256 + 255) / 256, 256, 0, stream>>>(Wl2, Wr2, W2th, W2tl, 64, 256,
                                                           128 * 256);

  // layer 1 (lo-plane store skipped: x1 is consumed hi-only by fused1)
  mfma_gemm_B<128, false><<<dim3((NN + 63) / 64, 8), 256, 0, stream>>>(
      x_hi, x_lo, W1th, W1tl, x1h, nullptr, NN, 512);
  fused1<<<NN, 64, 0, stream>>>(srcs, row_ptr, ea_r, x1h, We1, att1, b1, h_hi, h_lo);

  // layer 2 (lo-plane store skipped: x2 is consumed hi-only by fused2)
  mfma_gemm_B<256, false><<<dim3((NN + 63) / 64, 2), 256, 0, stream>>>(
      h_hi, h_lo, W2th, W2tl, x2h, nullptr, NN, 128);
  fused2<<<NN, 64, 0, stream>>>(srcs, row_ptr, (const float*)ea_r, x2h, We2, att2,
                                b2, out);
}

// Round 12
// 270.998 us; speedup vs baseline: 1.0255x; 1.0255x over previous
//
#include <hip/hip_runtime.h>

#define NN 20000
#define NE 320000

typedef __attribute__((ext_vector_type(8))) short bf16x8;
typedef __attribute__((ext_vector_type(4))) float f32x4;

__device__ __forceinline__ float bf2f(unsigned short u) {
  union { unsigned int i; float f; } v; v.i = ((unsigned int)u) << 16; return v.f;
}
__device__ __forceinline__ unsigned short f2bf(float f) {
  union { float f; unsigned int i; } v; v.f = f;
  unsigned int r = v.i + 0x7FFF + ((v.i >> 16) & 1);
  return (unsigned short)(r >> 16);
}
__device__ __forceinline__ float4 ld_bf4(const unsigned short* p) {
  ushort4 u = *(const ushort4*)p;
  float4 f;
  f.x = bf2f(u.x); f.y = bf2f(u.y); f.z = bf2f(u.z); f.w = bf2f(u.w);
  return f;
}

// 16-lane (DPP row) sum: 4 VALU adds, no LGKM. All 16 lanes end with the total.
__device__ __forceinline__ float rsum16(float v) {
  v += __int_as_float(__builtin_amdgcn_mov_dpp(__float_as_int(v), 0x121, 0xF, 0xF, true));
  v += __int_as_float(__builtin_amdgcn_mov_dpp(__float_as_int(v), 0x122, 0xF, 0xF, true));
  v += __int_as_float(__builtin_amdgcn_mov_dpp(__float_as_int(v), 0x124, 0xF, 0xF, true));
  v += __int_as_float(__builtin_amdgcn_mov_dpp(__float_as_int(v), 0x128, 0xF, 0xF, true));
  return v;
}

// ---------------- helpers (proven forms) ----------------

__device__ __forceinline__ void ea_fma(float4& v, const float4 ea, const float4* w) {
  v.x += ea.x * w[0].x + ea.y * w[1].x + ea.z * w[2].x + ea.w * w[3].x;
  v.y += ea.x * w[0].y + ea.y * w[1].y + ea.z * w[2].y + ea.w * w[3].y;
  v.z += ea.x * w[0].z + ea.y * w[1].z + ea.z * w[2].z + ea.w * w[3].z;
  v.w += ea.x * w[0].w + ea.y * w[1].w + ea.z * w[2].w + ea.w * w[3].w;
}

__device__ __forceinline__ void leaky4(float4& v) {
  v.x = (v.x > 0.f) ? v.x : 0.2f * v.x;
  v.y = (v.y > 0.f) ? v.y : 0.2f * v.y;
  v.z = (v.z > 0.f) ? v.z : 0.2f * v.z;
  v.w = (v.w > 0.f) ? v.w : 0.2f * v.w;
}

// ---------------- CSR construction ----------------

__global__ void count_dst(const int* __restrict__ ei, int* __restrict__ counts) {
  int e = blockIdx.x * blockDim.x + threadIdx.x;
  if (e < NE) atomicAdd(&counts[ei[NE + e]], 1);
}

__global__ void scan_local(const int* __restrict__ counts, int* __restrict__ tmp,
                           int* __restrict__ bsum) {
  __shared__ int sh[1024];
  int b = blockIdx.x, t = threadIdx.x, i = b * 1024 + t;
  int v = (i < NN) ? counts[i] : 0;
  sh[t] = v;
  __syncthreads();
  for (int off = 1; off < 1024; off <<= 1) {
    int add = (t >= off) ? sh[t - off] : 0;
    __syncthreads();
    sh[t] += add;
    __syncthreads();
  }
  if (i < NN) tmp[i] = sh[t];
  if (t == 1023) bsum[b] = sh[t];
}

// round-11: wave-parallel exclusive scan (was a 1-thread serial loop: ~20 dependent
// global round-trips on the CSR critical path). Integer-exact.
__global__ void scan_bsum(int* __restrict__ bsum, int nb) {
  int lane = threadIdx.x;
  int v = (lane < nb) ? bsum[lane] : 0;
  for (int off = 1; off < 64; off <<= 1) {
    int t = __shfl_up(v, off);
    if (lane >= off) v += t;
  }
  int excl = __shfl_up(v, 1);
  if (lane == 0) excl = 0;
  if (lane < nb) bsum[lane] = excl;
}

__global__ void scan_finish(const int* __restrict__ counts, const int* __restrict__ tmp,
                            const int* __restrict__ bsum, int* __restrict__ row_ptr,
                            int* __restrict__ cursor) {
  int i = blockIdx.x * 256 + threadIdx.x;
  if (i == 0) row_ptr[0] = 0;
  if (i < NN) {
    int incl = tmp[i] + bsum[i >> 10];
    row_ptr[i + 1] = incl;
    cursor[i] = incl - counts[i];
  }
}

__global__ void scatter_edges(const int* __restrict__ ei, const float4* __restrict__ eattr4,
                              int* __restrict__ cursor, int* __restrict__ srcs,
                              float4* __restrict__ ea_r) {
  int e = blockIdx.x * blockDim.x + threadIdx.x;
  if (e < NE) {
    int d = ei[NE + e];
    int pos = atomicAdd(&cursor[d], 1);
    srcs[pos] = ei[e];
    float4 a0 = eattr4[(size_t)e * 4 + 0];
    float4 a1 = eattr4[(size_t)e * 4 + 1];
    float4 a2 = eattr4[(size_t)e * 4 + 2];
    float4 a3 = eattr4[(size_t)e * 4 + 3];
    ea_r[(size_t)pos * 4 + 0] = a0;
    ea_r[(size_t)pos * 4 + 1] = a1;
    ea_r[(size_t)pos * 4 + 2] = a2;
    ea_r[(size_t)pos * 4 + 3] = a3;
  }
}

// ---------------- split-bf16 conversion ----------------

__global__ void split_bf16(const float* __restrict__ src, unsigned short* __restrict__ hi,
                           unsigned short* __restrict__ lo, int n) {
  int i = blockIdx.x * 256 + threadIdx.x;
  if (i < n) {
    float v = src[i];
    unsigned short h = f2bf(v);
    hi[i] = h;
    lo[i] = f2bf(v - bf2f(h));
  }
}

__global__ void cat_split_T(const float* __restrict__ W1, const float* __restrict__ W2,
                            unsigned short* __restrict__ hi, unsigned short* __restrict__ lo,
                            int N0, int K, int total) {
  int i = blockIdx.x * 256 + threadIdx.x;
  if (i < total) {
    int n = i / K, k = i - n * K;
    float v = (n < N0) ? W1[k * N0 + n] : W2[k * N0 + n - N0];
    unsigned short h = f2bf(v);
    hi[i] = h;
    lo[i] = f2bf(v - bf2f(h));
  }
}

// ---------------- split-bf16 MFMA GEMM, B-resident-in-LDS ----------------
// WLO=false skips the lo-plane C store (dead for x1/x2: fused kernels read hi only).

template<int K, bool WLO>
__global__ __launch_bounds__(256) void mfma_gemm_B(
    const unsigned short* __restrict__ Ah, const unsigned short* __restrict__ Al,
    const unsigned short* __restrict__ Bth, const unsigned short* __restrict__ Btl,
    unsigned short* __restrict__ Ch, unsigned short* __restrict__ Cl, int M, int N) {
  constexpr int BP = K + 24;
  __shared__ unsigned short Bsh[64 * BP], Bsl[64 * BP];
  int t = threadIdx.x;
  int wv = t >> 6, lane = t & 63;
  int quad = lane >> 4, mrow = lane & 15;
  int m0 = blockIdx.x * 64;
  int n0 = blockIdx.y * 64;

  for (int idx = t; idx < 64 * K / 8; idx += 256) {
    int n = idx / (K / 8), seg = (idx - n * (K / 8)) * 8;
    *(uint4*)(Bsh + n * BP + seg) = *(const uint4*)(Bth + (size_t)(n0 + n) * K + seg);
    *(uint4*)(Bsl + n * BP + seg) = *(const uint4*)(Btl + (size_t)(n0 + n) * K + seg);
  }
  __syncthreads();

  f32x4 acc[4];
#pragma unroll
  for (int i = 0; i < 4; ++i) acc[i] = (f32x4){0.f, 0.f, 0.f, 0.f};

  int arow = m0 + wv * 16 + mrow;
  if (arow >= M) arow = M - 1;
  const unsigned short* ap_h = Ah + (size_t)arow * K + quad * 8;
  const unsigned short* ap_l = Al + (size_t)arow * K + quad * 8;

  for (int ks = 0; ks < K; ks += 32) {
    bf16x8 ah = *(const bf16x8*)(ap_h + ks);
    bf16x8 al = *(const bf16x8*)(ap_l + ks);
#pragma unroll
    for (int nt = 0; nt < 4; ++nt) {
      bf16x8 bh = *(const bf16x8*)(Bsh + (nt * 16 + mrow) * BP + ks + quad * 8);
      bf16x8 bl = *(const bf16x8*)(Bsl + (nt * 16 + mrow) * BP + ks + quad * 8);
      acc[nt] = __builtin_amdgcn_mfma_f32_16x16x32_bf16(ah, bh, acc[nt], 0, 0, 0);
      acc[nt] = __builtin_amdgcn_mfma_f32_16x16x32_bf16(ah, bl, acc[nt], 0, 0, 0);
      acc[nt] = __builtin_amdgcn_mfma_f32_16x16x32_bf16(al, bh, acc[nt], 0, 0, 0);
    }
  }
#pragma unroll
  for (int nt = 0; nt < 4; ++nt)
#pragma unroll
    for (int r = 0; r < 4; ++r) {
      int row = m0 + wv * 16 + quad * 4 + r;
      if (row < M) {
        float f = acc[nt][r];
        unsigned short h = f2bf(f);
        size_t o = (size_t)row * N + n0 + nt * 16 + mrow;
        Ch[o] = h;
        if constexpr (WLO) Cl[o] = f2bf(f - bf2f(h));
      }
    }
}

// ---------------- FUSED layer 1 (round-9 winner, byte-identical) ----------
// One wave per node (1-wave blocks), 2 edges/iter, scalar srcs/ea (s_load path),
// SGPR ea coefficients via compiler-chosen v_fmac vdst,s,v.
// CLOSED questions (all regressed): 4-wide (r3, r6), 2-waves/node (r4), manual
// prefetch pipeline (r8), packed v_pk_fma_f32 via inline asm (r0, r10).

__global__ __launch_bounds__(64, 1) void fused1(
    const int* __restrict__ srcs, const int* __restrict__ row_ptr,
    const float4* __restrict__ ea_r, const unsigned short* __restrict__ xh,
    const float* __restrict__ We, const float* __restrict__ att,
    const float* __restrict__ bias, unsigned short* __restrict__ h_hi,
    unsigned short* __restrict__ h_lo) {
  int lane = threadIdx.x & 63;
  int n = __builtin_amdgcn_readfirstlane(blockIdx.x);
  int col = (lane >> 4) * 64 + (lane & 15) * 4;
  float4 we[16];
#pragma unroll
  for (int k = 0; k < 16; ++k) we[k] = *(const float4*)(We + k * 256 + col);
  float4 at = *(const float4*)(att + col);
  float4 ra = ld_bf4(xh + (size_t)n * 512 + 256 + col);
  int beg = __builtin_amdgcn_readfirstlane(row_ptr[n]);
  int end = __builtin_amdgcn_readfirstlane(row_ptr[n + 1]);
  float den0 = 0.f, den1 = 0.f;
  float4 A0 = {0, 0, 0, 0}, A1 = {0, 0, 0, 0};
  int i = beg;
  for (; i + 2 <= end; i += 2) {
    int s0 = __builtin_amdgcn_readfirstlane(srcs[i]);
    int s1 = __builtin_amdgcn_readfirstlane(srcs[i + 1]);
    float4 xa = ld_bf4(xh + (size_t)s0 * 512 + col);
    float4 xb = ld_bf4(xh + (size_t)s1 * 512 + col);
    const float4* ep = ea_r + (size_t)i * 4;
    float4 p0 = ep[0], p1 = ep[1], p2 = ep[2], p3 = ep[3];
    float4 q0 = ep[4], q1 = ep[5], q2 = ep[6], q3 = ep[7];
    float4 v0, v1;
    v0.x = xa.x + ra.x; v0.y = xa.y + ra.y; v0.z = xa.z + ra.z; v0.w = xa.w + ra.w;
    v1.x = xb.x + ra.x; v1.y = xb.y + ra.y; v1.z = xb.z + ra.z; v1.w = xb.w + ra.w;
    ea_fma(v0, p0, we + 0); ea_fma(v0, p1, we + 4);
    ea_fma(v0, p2, we + 8); ea_fma(v0, p3, we + 12);
    ea_fma(v1, q0, we + 0); ea_fma(v1, q1, we + 4);
    ea_fma(v1, q2, we + 8); ea_fma(v1, q3, we + 12);
    leaky4(v0); leaky4(v1);
    float sA = at.x * v0.x + at.y * v0.y + at.z * v0.z + at.w * v0.w;
    float sB = at.x * v1.x + at.y * v1.y + at.z * v1.z + at.w * v1.w;
    sA = rsum16(sA);
    sB = rsum16(sB);
    float pA = __expf(sA), pB = __expf(sB);
    den0 += pA; den1 += pB;
    A0.x += pA * xa.x; A0.y += pA * xa.y; A0.z += pA * xa.z; A0.w += pA * xa.w;
    A1.x += pB * xb.x; A1.y += pB * xb.y; A1.z += pB * xb.z; A1.w += pB * xb.w;
  }
  if (i < end) {  // tail edge
    int s0 = __builtin_amdgcn_readfirstlane(srcs[i]);
    float4 xa = ld_bf4(xh + (size_t)s0 * 512 + col);
    const float4* ep = ea_r + (size_t)i * 4;
    float4 p0 = ep[0], p1 = ep[1], p2 = ep[2], p3 = ep[3];
    float4 v0;
    v0.x = xa.x + ra.x; v0.y = xa.y + ra.y; v0.z = xa.z + ra.z; v0.w = xa.w + ra.w;
    ea_fma(v0, p0, we + 0); ea_fma(v0, p1, we + 4);
    ea_fma(v0, p2, we + 8); ea_fma(v0, p3, we + 12);
    leaky4(v0);
    float sA = at.x * v0.x + at.y * v0.y + at.z * v0.z + at.w * v0.w;
    sA = rsum16(sA);
    float pA = __expf(sA);
    den0 += pA;
    A0.x += pA * xa.x; A0.y += pA * xa.y; A0.z += pA * xa.z; A0.w += pA * xa.w;
  }
  float D = den0 + den1;
  float4 A;
  A.x = A0.x + A1.x;
  A.y = A0.y + A1.y;
  A.z = A0.z + A1.z;
  A.w = A0.w + A1.w;
  bool has = end > beg;
  float rd = has ? 1.f / D : 0.f;
  float4 b4 = *(const float4*)(bias + col);
  float4 o;
  o.x = A.x * rd + b4.x;
  o.y = A.y * rd + b4.y;
  o.z = A.z * rd + b4.z;
  o.w = A.w * rd + b4.w;
  o.x = (o.x > 0.f) ? o.x : (__expf(o.x) - 1.f);
  o.y = (o.y > 0.f) ? o.y : (__expf(o.y) - 1.f);
  o.z = (o.z > 0.f) ? o.z : (__expf(o.z) - 1.f);
  o.w = (o.w > 0.f) ? o.w : (__expf(o.w) - 1.f);
  ushort4 oh, ol;
  oh.x = f2bf(o.x); ol.x = f2bf(o.x - bf2f(oh.x));
  oh.y = f2bf(o.y); ol.y = f2bf(o.y - bf2f(oh.y));
  oh.z = f2bf(o.z); ol.z = f2bf(o.z - bf2f(oh.z));
  oh.w = f2bf(o.w); ol.w = f2bf(o.w - bf2f(oh.w));
  *(ushort4*)(h_hi + (size_t)n * 256 + col) = oh;
  *(ushort4*)(h_lo + (size_t)n * 256 + col) = ol;
}

// ---------------- FUSED layer 2 (round-9 winner, byte-identical) ----------
// Whole wave per edge, 1 channel/lane (C=64), 2 edges/iter: srcs[i] readfirstlane'd,
// ea_r wave-uniform -> scalar s_loads, We column in 16 VGPRs with SGPR ea coefficients.

__global__ __launch_bounds__(64, 1) void fused2(
    const int* __restrict__ srcs, const int* __restrict__ row_ptr,
    const float* __restrict__ ea_r, const unsigned short* __restrict__ xh,
    const float* __restrict__ We, const float* __restrict__ att,
    const float* __restrict__ bias, float* __restrict__ out) {
  int lane = threadIdx.x & 63;
  int n = __builtin_amdgcn_readfirstlane(blockIdx.x);
  float wcol[16];
#pragma unroll
  for (int k = 0; k < 16; ++k) wcol[k] = We[k * 64 + lane];
  float at = att[lane];
  float ra = bf2f(xh[(size_t)n * 128 + 64 + lane]);
  int beg = __builtin_amdgcn_readfirstlane(row_ptr[n]);
  int end = __builtin_amdgcn_readfirstlane(row_ptr[n + 1]);
  float den0 = 0.f, den1 = 0.f;
  float A0 = 0.f, A1 = 0.f;
  int i = beg;
  for (; i + 2 <= end; i += 2) {
    int s0 = __builtin_amdgcn_readfirstlane(srcs[i]);
    int s1 = __builtin_amdgcn_readfirstlane(srcs[i + 1]);
    float xa0 = bf2f(xh[(size_t)s0 * 128 + lane]);
    float xa1 = bf2f(xh[(size_t)s1 * 128 + lane]);
    const float* ep = ea_r + (size_t)i * 16;  // 32 scalar floats (edges i, i+1)
    float v0 = xa0 + ra, v1 = xa1 + ra;
#pragma unroll
    for (int k = 0; k < 16; ++k) v0 += ep[k] * wcol[k];
#pragma unroll
    for (int k = 0; k < 16; ++k) v1 += ep[16 + k] * wcol[k];
    v0 = fmaxf(v0, 0.2f * v0);
    v1 = fmaxf(v1, 0.2f * v1);
    float sA = at * v0, sB = at * v1;
    sA = rsum16(sA); sB = rsum16(sB);
    sA += __shfl_xor(sA, 16); sB += __shfl_xor(sB, 16);
    sA += __shfl_xor(sA, 32); sB += __shfl_xor(sB, 32);
    float pA = __expf(sA), pB = __expf(sB);
    den0 += pA; den1 += pB;
    A0 += pA * xa0; A1 += pB * xa1;
  }
  if (i < end) {  // tail edge
    int s0 = __builtin_amdgcn_readfirstlane(srcs[i]);
    float xa0 = bf2f(xh[(size_t)s0 * 128 + lane]);
    const float* ep = ea_r + (size_t)i * 16;
    float v0 = xa0 + ra;
#pragma unroll
    for (int k = 0; k < 16; ++k) v0 += ep[k] * wcol[k];
    v0 = fmaxf(v0, 0.2f * v0);
    float sA = at * v0;
    sA = rsum16(sA);
    sA += __shfl_xor(sA, 16);
    sA += __shfl_xor(sA, 32);
    float pA = __expf(sA);
    den0 += pA;
    A0 += pA * xa0;
  }
  float D = den0 + den1;
  float A = A0 + A1;
  bool has = end > beg;
  float o = (has ? A / D : 0.f) + bias[lane];
  out[(size_t)n * 64 + lane] = o;
}

// ---------------- launch ----------------

extern "C" void kernel_launch(void* const* d_in, const int* in_sizes, int n_in,
                              void* d_out, int out_size, void* d_ws, size_t ws_size,
                              hipStream_t stream) {
  const float* x    = (const float*)d_in[0];
  const int*   ei   = (const int*)  d_in[1];
  const float* eatt = (const float*)d_in[2];
  const float* Wl1  = (const float*)d_in[3];
  const float* Wr1  = (const float*)d_in[4];
  const float* We1  = (const float*)d_in[5];
  const float* att1 = (const float*)d_in[6];
  const float* b1   = (const float*)d_in[7];
  const float* Wl2  = (const float*)d_in[8];
  const float* Wr2  = (const float*)d_in[9];
  const float* We2  = (const float*)d_in[10];
  const float* att2 = (const float*)d_in[11];
  const float* b2   = (const float*)d_in[12];
  float* out = (float*)d_out;

  char* wsb = (char*)d_ws;
  size_t off = 0;
  auto alloc = [&](size_t bytes) {
    char* p = wsb + off;
    off += (bytes + 255) & ~(size_t)255;
    return p;
  };
  int* counts    = (int*)alloc((size_t)NN * 4);
  int* tmp       = (int*)alloc((size_t)NN * 4);
  int* bsum      = (int*)alloc(32 * 4);
  int* row_ptr   = (int*)alloc((size_t)(NN + 1) * 4);
  int* cursor    = (int*)alloc((size_t)NN * 4);
  int* srcs      = (int*)alloc((size_t)NE * 4);
  float4* ea_r   = (float4*)alloc((size_t)NE * 16 * 4);
  unsigned short* x_hi  = (unsigned short*)alloc((size_t)NN * 128 * 2);
  unsigned short* x_lo  = (unsigned short*)alloc((size_t)NN * 128 * 2);
  unsigned short* W1th  = (unsigned short*)alloc((size_t)512 * 128 * 2);
  unsigned short* W1tl  = (unsigned short*)alloc((size_t)512 * 128 * 2);
  unsigned short* W2th  = (unsigned short*)alloc((size_t)128 * 256 * 2);
  unsigned short* W2tl  = (unsigned short*)alloc((size_t)128 * 256 * 2);
  unsigned short* h_hi  = (unsigned short*)alloc((size_t)NN * 256 * 2);
  unsigned short* h_lo  = (unsigned short*)alloc((size_t)NN * 256 * 2);
  unsigned short* x1h   = (unsigned short*)alloc((size_t)NN * 512 * 2);
  unsigned short* x2h   = (unsigned short*)alloc((size_t)NN * 128 * 2);

  // CSR by destination (+ srcs + edge_attr reorder)
  hipMemsetAsync(counts, 0, (size_t)NN * 4, stream);
  count_dst<<<(NE + 255) / 256, 256, 0, stream>>>(ei, counts);
  scan_local<<<(NN + 1023) / 1024, 1024, 0, stream>>>(counts, tmp, bsum);
  scan_bsum<<<1, 64, 0, stream>>>(bsum, (NN + 1023) / 1024);
  scan_finish<<<(NN + 255) / 256, 256, 0, stream>>>(counts, tmp, bsum, row_ptr, cursor);
  scatter_edges<<<(NE + 255) / 256, 256, 0, stream>>>(ei, (const float4*)eatt, cursor,
                                                      srcs, ea_r);

  // split-bf16 conversions (W transposed for the B-resident GEMM)
  split_bf16<<<(NN * 128 + 255) / 256, 256, 0, stream>>>(x, x_hi, x_lo, NN * 128);
  cat_split_T<<<(512 * 128 + 255) / 256, 256, 0, stream>>>(Wl1, Wr1, W1th, W1tl, 256, 128,
                                                           512 * 128);
  cat_split_T<<<(128 * 256 + 255) / 256, 256, 0, stream>>>(Wl2, Wr2, W2th, W2tl, 64, 256,
                                                           128 * 256);

  // layer 1 (lo-plane store skipped: x1 is consumed hi-only by fused1)
  mfma_gemm_B<128, false><<<dim3((NN + 63) / 64, 8), 256, 0, stream>>>(
      x_hi, x_lo, W1th, W1tl, x1h, nullptr, NN, 512);
  fused1<<<NN, 64, 0, stream>>>(srcs, row_ptr, ea_r, x1h, We1, att1, b1, h_hi, h_lo);

  // layer 2 (lo-plane store skipped: x2 is consumed hi-only by fused2)
  mfma_gemm_B<256, false><<<dim3((NN + 63) / 64, 2), 256, 0, stream>>>(
      h_hi, h_lo, W2th, W2tl, x2h, nullptr, NN, 128);
  fused2<<<NN, 64, 0, stream>>>(srcs, row_ptr, (const float*)ea_r, x2h, We2, att2,
                                b2, out);
}

// Round 13
// 267.786 us; speedup vs baseline: 1.0378x; 1.0120x over previous
//
#include <hip/hip_runtime.h>

#define NN 20000
#define NE 320000

typedef __attribute__((ext_vector_type(8))) short bf16x8;
typedef __attribute__((ext_vector_type(4))) float f32x4;

__device__ __forceinline__ float bf2f(unsigned short u) {
  union { unsigned int i; float f; } v; v.i = ((unsigned int)u) << 16; return v.f;
}
__device__ __forceinline__ unsigned short f2bf(float f) {
  union { float f; unsigned int i; } v; v.f = f;
  unsigned int r = v.i + 0x7FFF + ((v.i >> 16) & 1);
  return (unsigned short)(r >> 16);
}
__device__ __forceinline__ float4 ld_bf4(const unsigned short* p) {
  ushort4 u = *(const ushort4*)p;
  float4 f;
  f.x = bf2f(u.x); f.y = bf2f(u.y); f.z = bf2f(u.z); f.w = bf2f(u.w);
  return f;
}

// 16-lane (DPP row) sum: 4 VALU adds, no LGKM. All 16 lanes end with the total.
__device__ __forceinline__ float rsum16(float v) {
  v += __int_as_float(__builtin_amdgcn_mov_dpp(__float_as_int(v), 0x121, 0xF, 0xF, true));
  v += __int_as_float(__builtin_amdgcn_mov_dpp(__float_as_int(v), 0x122, 0xF, 0xF, true));
  v += __int_as_float(__builtin_amdgcn_mov_dpp(__float_as_int(v), 0x124, 0xF, 0xF, true));
  v += __int_as_float(__builtin_amdgcn_mov_dpp(__float_as_int(v), 0x128, 0xF, 0xF, true));
  return v;
}

// ---------------- helpers (proven forms) ----------------

__device__ __forceinline__ void ea_fma(float4& v, const float4 ea, const float4* w) {
  v.x += ea.x * w[0].x + ea.y * w[1].x + ea.z * w[2].x + ea.w * w[3].x;
  v.y += ea.x * w[0].y + ea.y * w[1].y + ea.z * w[2].y + ea.w * w[3].y;
  v.z += ea.x * w[0].z + ea.y * w[1].z + ea.z * w[2].z + ea.w * w[3].z;
  v.w += ea.x * w[0].w + ea.y * w[1].w + ea.z * w[2].w + ea.w * w[3].w;
}

__device__ __forceinline__ void leaky4(float4& v) {
  v.x = (v.x > 0.f) ? v.x : 0.2f * v.x;
  v.y = (v.y > 0.f) ? v.y : 0.2f * v.y;
  v.z = (v.z > 0.f) ? v.z : 0.2f * v.z;
  v.w = (v.w > 0.f) ? v.w : 0.2f * v.w;
}

// ---------------- CSR construction ----------------

__global__ void count_dst(const int* __restrict__ ei, int* __restrict__ counts) {
  int e = blockIdx.x * blockDim.x + threadIdx.x;
  if (e < NE) atomicAdd(&counts[ei[NE + e]], 1);
}

__global__ void scan_local(const int* __restrict__ counts, int* __restrict__ tmp,
                           int* __restrict__ bsum) {
  __shared__ int sh[1024];
  int b = blockIdx.x, t = threadIdx.x, i = b * 1024 + t;
  int v = (i < NN) ? counts[i] : 0;
  sh[t] = v;
  __syncthreads();
  for (int off = 1; off < 1024; off <<= 1) {
    int add = (t >= off) ? sh[t - off] : 0;
    __syncthreads();
    sh[t] += add;
    __syncthreads();
  }
  if (i < NN) tmp[i] = sh[t];
  if (t == 1023) bsum[b] = sh[t];
}

// wave-parallel exclusive scan (round 11). Integer-exact.
__global__ void scan_bsum(int* __restrict__ bsum, int nb) {
  int lane = threadIdx.x;
  int v = (lane < nb) ? bsum[lane] : 0;
  for (int off = 1; off < 64; off <<= 1) {
    int t = __shfl_up(v, off);
    if (lane >= off) v += t;
  }
  int excl = __shfl_up(v, 1);
  if (lane == 0) excl = 0;
  if (lane < nb) bsum[lane] = excl;
}

__global__ void scan_finish(const int* __restrict__ counts, const int* __restrict__ tmp,
                            const int* __restrict__ bsum, int* __restrict__ row_ptr,
                            int* __restrict__ cursor) {
  int i = blockIdx.x * 256 + threadIdx.x;
  if (i == 0) row_ptr[0] = 0;
  if (i < NN) {
    int incl = tmp[i] + bsum[i >> 10];
    row_ptr[i + 1] = incl;
    cursor[i] = incl - counts[i];
  }
}

// round-12: scatter only (src, edge_id) as one 8-B store. The 20 MB edge_attr copy is
// GONE — consumers read the ORIGINAL edge_attr via the scalar-loaded edge id (the ea
// stream is a no-reuse cold-miss stream either way; reordering it bought nothing but
// cost a 40+ MB copy kernel).
__global__ void scatter_edges(const int* __restrict__ ei, int* __restrict__ cursor,
                              int2* __restrict__ sp) {
  int e = blockIdx.x * blockDim.x + threadIdx.x;
  if (e < NE) {
    int d = ei[NE + e];
    int pos = atomicAdd(&cursor[d], 1);
    sp[pos] = make_int2(ei[e], e);
  }
}

// ---------------- split-bf16 conversion ----------------

__global__ void split_bf16(const float* __restrict__ src, unsigned short* __restrict__ hi,
                           unsigned short* __restrict__ lo, int n) {
  int i = blockIdx.x * 256 + threadIdx.x;
  if (i < n) {
    float v = src[i];
    unsigned short h = f2bf(v);
    hi[i] = h;
    lo[i] = f2bf(v - bf2f(h));
  }
}

__global__ void cat_split_T(const float* __restrict__ W1, const float* __restrict__ W2,
                            unsigned short* __restrict__ hi, unsigned short* __restrict__ lo,
                            int N0, int K, int total) {
  int i = blockIdx.x * 256 + threadIdx.x;
  if (i < total) {
    int n = i / K, k = i - n * K;
    float v = (n < N0) ? W1[k * N0 + n] : W2[k * N0 + n - N0];
    unsigned short h = f2bf(v);
    hi[i] = h;
    lo[i] = f2bf(v - bf2f(h));
  }
}

// ---------------- split-bf16 MFMA GEMM, B-resident-in-LDS ----------------
// WLO=false skips the lo-plane C store (dead for x1/x2: fused kernels read hi only).

template<int K, bool WLO>
__global__ __launch_bounds__(256) void mfma_gemm_B(
    const unsigned short* __restrict__ Ah, const unsigned short* __restrict__ Al,
    const unsigned short* __restrict__ Bth, const unsigned short* __restrict__ Btl,
    unsigned short* __restrict__ Ch, unsigned short* __restrict__ Cl, int M, int N) {
  constexpr int BP = K + 24;
  __shared__ unsigned short Bsh[64 * BP], Bsl[64 * BP];
  int t = threadIdx.x;
  int wv = t >> 6, lane = t & 63;
  int quad = lane >> 4, mrow = lane & 15;
  int m0 = blockIdx.x * 64;
  int n0 = blockIdx.y * 64;

  for (int idx = t; idx < 64 * K / 8; idx += 256) {
    int n = idx / (K / 8), seg = (idx - n * (K / 8)) * 8;
    *(uint4*)(Bsh + n * BP + seg) = *(const uint4*)(Bth + (size_t)(n0 + n) * K + seg);
    *(uint4*)(Bsl + n * BP + seg) = *(const uint4*)(Btl + (size_t)(n0 + n) * K + seg);
  }
  __syncthreads();

  f32x4 acc[4];
#pragma unroll
  for (int i = 0; i < 4; ++i) acc[i] = (f32x4){0.f, 0.f, 0.f, 0.f};

  int arow = m0 + wv * 16 + mrow;
  if (arow >= M) arow = M - 1;
  const unsigned short* ap_h = Ah + (size_t)arow * K + quad * 8;
  const unsigned short* ap_l = Al + (size_t)arow * K + quad * 8;

  for (int ks = 0; ks < K; ks += 32) {
    bf16x8 ah = *(const bf16x8*)(ap_h + ks);
    bf16x8 al = *(const bf16x8*)(ap_l + ks);
#pragma unroll
    for (int nt = 0; nt < 4; ++nt) {
      bf16x8 bh = *(const bf16x8*)(Bsh + (nt * 16 + mrow) * BP + ks + quad * 8);
      bf16x8 bl = *(const bf16x8*)(Bsl + (nt * 16 + mrow) * BP + ks + quad * 8);
      acc[nt] = __builtin_amdgcn_mfma_f32_16x16x32_bf16(ah, bh, acc[nt], 0, 0, 0);
      acc[nt] = __builtin_amdgcn_mfma_f32_16x16x32_bf16(ah, bl, acc[nt], 0, 0, 0);
      acc[nt] = __builtin_amdgcn_mfma_f32_16x16x32_bf16(al, bh, acc[nt], 0, 0, 0);
    }
  }
#pragma unroll
  for (int nt = 0; nt < 4; ++nt)
#pragma unroll
    for (int r = 0; r < 4; ++r) {
      int row = m0 + wv * 16 + quad * 4 + r;
      if (row < M) {
        float f = acc[nt][r];
        unsigned short h = f2bf(f);
        size_t o = (size_t)row * N + n0 + nt * 16 + mrow;
        Ch[o] = h;
        if constexpr (WLO) Cl[o] = f2bf(f - bf2f(h));
      }
    }
}

// ---------------- FUSED layer 1 (round-9 structure; ea via edge-id indirection) ----------
// One wave per node (1-wave blocks), 2 edges/iter, scalar (src,edge) pairs s_loaded,
// ea read from the ORIGINAL edge_attr at the scalar edge-id base (s_load path, SGPR
// coefficients — unchanged pattern, base now per-edge instead of linear).
// CLOSED questions (all regressed): 4-wide (r3, r6), 2-waves/node (r4), manual
// prefetch pipeline (r8), packed v_pk_fma_f32 via inline asm (r0, r10).

__global__ __launch_bounds__(64, 1) void fused1(
    const int2* __restrict__ sp, const int* __restrict__ row_ptr,
    const float* __restrict__ eatt, const unsigned short* __restrict__ xh,
    const float* __restrict__ We, const float* __restrict__ att,
    const float* __restrict__ bias, unsigned short* __restrict__ h_hi,
    unsigned short* __restrict__ h_lo) {
  int lane = threadIdx.x & 63;
  int n = __builtin_amdgcn_readfirstlane(blockIdx.x);
  int col = (lane >> 4) * 64 + (lane & 15) * 4;
  float4 we[16];
#pragma unroll
  for (int k = 0; k < 16; ++k) we[k] = *(const float4*)(We + k * 256 + col);
  float4 at = *(const float4*)(att + col);
  float4 ra = ld_bf4(xh + (size_t)n * 512 + 256 + col);
  int beg = __builtin_amdgcn_readfirstlane(row_ptr[n]);
  int end = __builtin_amdgcn_readfirstlane(row_ptr[n + 1]);
  float den0 = 0.f, den1 = 0.f;
  float4 A0 = {0, 0, 0, 0}, A1 = {0, 0, 0, 0};
  int i = beg;
  for (; i + 2 <= end; i += 2) {
    int2 sp0 = sp[i], sp1 = sp[i + 1];
    int s0 = __builtin_amdgcn_readfirstlane(sp0.x);
    int e0 = __builtin_amdgcn_readfirstlane(sp0.y);
    int s1 = __builtin_amdgcn_readfirstlane(sp1.x);
    int e1 = __builtin_amdgcn_readfirstlane(sp1.y);
    float4 xa = ld_bf4(xh + (size_t)s0 * 512 + col);
    float4 xb = ld_bf4(xh + (size_t)s1 * 512 + col);
    const float4* ep0 = (const float4*)(eatt + (size_t)e0 * 16);
    const float4* ep1 = (const float4*)(eatt + (size_t)e1 * 16);
    float4 p0 = ep0[0], p1 = ep0[1], p2 = ep0[2], p3 = ep0[3];
    float4 q0 = ep1[0], q1 = ep1[1], q2 = ep1[2], q3 = ep1[3];
    float4 v0, v1;
    v0.x = xa.x + ra.x; v0.y = xa.y + ra.y; v0.z = xa.z + ra.z; v0.w = xa.w + ra.w;
    v1.x = xb.x + ra.x; v1.y = xb.y + ra.y; v1.z = xb.z + ra.z; v1.w = xb.w + ra.w;
    ea_fma(v0, p0, we + 0); ea_fma(v0, p1, we + 4);
    ea_fma(v0, p2, we + 8); ea_fma(v0, p3, we + 12);
    ea_fma(v1, q0, we + 0); ea_fma(v1, q1, we + 4);
    ea_fma(v1, q2, we + 8); ea_fma(v1, q3, we + 12);
    leaky4(v0); leaky4(v1);
    float sA = at.x * v0.x + at.y * v0.y + at.z * v0.z + at.w * v0.w;
    float sB = at.x * v1.x + at.y * v1.y + at.z * v1.z + at.w * v1.w;
    sA = rsum16(sA);
    sB = rsum16(sB);
    float pA = __expf(sA), pB = __expf(sB);
    den0 += pA; den1 += pB;
    A0.x += pA * xa.x; A0.y += pA * xa.y; A0.z += pA * xa.z; A0.w += pA * xa.w;
    A1.x += pB * xb.x; A1.y += pB * xb.y; A1.z += pB * xb.z; A1.w += pB * xb.w;
  }
  if (i < end) {  // tail edge
    int2 sp0 = sp[i];
    int s0 = __builtin_amdgcn_readfirstlane(sp0.x);
    int e0 = __builtin_amdgcn_readfirstlane(sp0.y);
    float4 xa = ld_bf4(xh + (size_t)s0 * 512 + col);
    const float4* ep0 = (const float4*)(eatt + (size_t)e0 * 16);
    float4 p0 = ep0[0], p1 = ep0[1], p2 = ep0[2], p3 = ep0[3];
    float4 v0;
    v0.x = xa.x + ra.x; v0.y = xa.y + ra.y; v0.z = xa.z + ra.z; v0.w = xa.w + ra.w;
    ea_fma(v0, p0, we + 0); ea_fma(v0, p1, we + 4);
    ea_fma(v0, p2, we + 8); ea_fma(v0, p3, we + 12);
    leaky4(v0);
    float sA = at.x * v0.x + at.y * v0.y + at.z * v0.z + at.w * v0.w;
    sA = rsum16(sA);
    float pA = __expf(sA);
    den0 += pA;
    A0.x += pA * xa.x; A0.y += pA * xa.y; A0.z += pA * xa.z; A0.w += pA * xa.w;
  }
  float D = den0 + den1;
  float4 A;
  A.x = A0.x + A1.x;
  A.y = A0.y + A1.y;
  A.z = A0.z + A1.z;
  A.w = A0.w + A1.w;
  bool has = end > beg;
  float rd = has ? 1.f / D : 0.f;
  float4 b4 = *(const float4*)(bias + col);
  float4 o;
  o.x = A.x * rd + b4.x;
  o.y = A.y * rd + b4.y;
  o.z = A.z * rd + b4.z;
  o.w = A.w * rd + b4.w;
  o.x = (o.x > 0.f) ? o.x : (__expf(o.x) - 1.f);
  o.y = (o.y > 0.f) ? o.y : (__expf(o.y) - 1.f);
  o.z = (o.z > 0.f) ? o.z : (__expf(o.z) - 1.f);
  o.w = (o.w > 0.f) ? o.w : (__expf(o.w) - 1.f);
  ushort4 oh, ol;
  oh.x = f2bf(o.x); ol.x = f2bf(o.x - bf2f(oh.x));
  oh.y = f2bf(o.y); ol.y = f2bf(o.y - bf2f(oh.y));
  oh.z = f2bf(o.z); ol.z = f2bf(o.z - bf2f(oh.z));
  oh.w = f2bf(o.w); ol.w = f2bf(o.w - bf2f(oh.w));
  *(ushort4*)(h_hi + (size_t)n * 256 + col) = oh;
  *(ushort4*)(h_lo + (size_t)n * 256 + col) = ol;
}

// ---------------- FUSED layer 2 (round-9 structure; ea via edge-id indirection) ----------
// Whole wave per edge, 1 channel/lane (C=64), 2 edges/iter: (src,edge) s_loaded,
// ea from original edge_attr at scalar edge-id base, We column in 16 VGPRs.

__global__ __launch_bounds__(64, 1) void fused2(
    const int2* __restrict__ sp, const int* __restrict__ row_ptr,
    const float* __restrict__ eatt, const unsigned short* __restrict__ xh,
    const float* __restrict__ We, const float* __restrict__ att,
    const float* __restrict__ bias, float* __restrict__ out) {
  int lane = threadIdx.x & 63;
  int n = __builtin_amdgcn_readfirstlane(blockIdx.x);
  float wcol[16];
#pragma unroll
  for (int k = 0; k < 16; ++k) wcol[k] = We[k * 64 + lane];
  float at = att[lane];
  float ra = bf2f(xh[(size_t)n * 128 + 64 + lane]);
  int beg = __builtin_amdgcn_readfirstlane(row_ptr[n]);
  int end = __builtin_amdgcn_readfirstlane(row_ptr[n + 1]);
  float den0 = 0.f, den1 = 0.f;
  float A0 = 0.f, A1 = 0.f;
  int i = beg;
  for (; i + 2 <= end; i += 2) {
    int2 sp0 = sp[i], sp1 = sp[i + 1];
    int s0 = __builtin_amdgcn_readfirstlane(sp0.x);
    int e0 = __builtin_amdgcn_readfirstlane(sp0.y);
    int s1 = __builtin_amdgcn_readfirstlane(sp1.x);
    int e1 = __builtin_amdgcn_readfirstlane(sp1.y);
    float xa0 = bf2f(xh[(size_t)s0 * 128 + lane]);
    float xa1 = bf2f(xh[(size_t)s1 * 128 + lane]);
    const float* ep0 = eatt + (size_t)e0 * 16;
    const float* ep1 = eatt + (size_t)e1 * 16;
    float v0 = xa0 + ra, v1 = xa1 + ra;
#pragma unroll
    for (int k = 0; k < 16; ++k) v0 += ep0[k] * wcol[k];
#pragma unroll
    for (int k = 0; k < 16; ++k) v1 += ep1[k] * wcol[k];
    v0 = fmaxf(v0, 0.2f * v0);
    v1 = fmaxf(v1, 0.2f * v1);
    float sA = at * v0, sB = at * v1;
    sA = rsum16(sA); sB = rsum16(sB);
    sA += __shfl_xor(sA, 16); sB += __shfl_xor(sB, 16);
    sA += __shfl_xor(sA, 32); sB += __shfl_xor(sB, 32);
    float pA = __expf(sA), pB = __expf(sB);
    den0 += pA; den1 += pB;
    A0 += pA * xa0; A1 += pB * xa1;
  }
  if (i < end) {  // tail edge
    int2 sp0 = sp[i];
    int s0 = __builtin_amdgcn_readfirstlane(sp0.x);
    int e0 = __builtin_amdgcn_readfirstlane(sp0.y);
    float xa0 = bf2f(xh[(size_t)s0 * 128 + lane]);
    const float* ep0 = eatt + (size_t)e0 * 16;
    float v0 = xa0 + ra;
#pragma unroll
    for (int k = 0; k < 16; ++k) v0 += ep0[k] * wcol[k];
    v0 = fmaxf(v0, 0.2f * v0);
    float sA = at * v0;
    sA = rsum16(sA);
    sA += __shfl_xor(sA, 16);
    sA += __shfl_xor(sA, 32);
    float pA = __expf(sA);
    den0 += pA;
    A0 += pA * xa0;
  }
  float D = den0 + den1;
  float A = A0 + A1;
  bool has = end > beg;
  float o = (has ? A / D : 0.f) + bias[lane];
  out[(size_t)n * 64 + lane] = o;
}

// ---------------- launch ----------------

extern "C" void kernel_launch(void* const* d_in, const int* in_sizes, int n_in,
                              void* d_out, int out_size, void* d_ws, size_t ws_size,
                              hipStream_t stream) {
  const float* x    = (const float*)d_in[0];
  const int*   ei   = (const int*)  d_in[1];
  const float* eatt = (const float*)d_in[2];
  const float* Wl1  = (const float*)d_in[3];
  const float* Wr1  = (const float*)d_in[4];
  const float* We1  = (const float*)d_in[5];
  const float* att1 = (const float*)d_in[6];
  const float* b1   = (const float*)d_in[7];
  const float* Wl2  = (const float*)d_in[8];
  const float* Wr2  = (const float*)d_in[9];
  const float* We2  = (const float*)d_in[10];
  const float* att2 = (const float*)d_in[11];
  const float* b2   = (const float*)d_in[12];
  float* out = (float*)d_out;

  char* wsb = (char*)d_ws;
  size_t off = 0;
  auto alloc = [&](size_t bytes) {
    char* p = wsb + off;
    off += (bytes + 255) & ~(size_t)255;
    return p;
  };
  int* counts    = (int*)alloc((size_t)NN * 4);
  int* tmp       = (int*)alloc((size_t)NN * 4);
  int* bsum      = (int*)alloc(32 * 4);
  int* row_ptr   = (int*)alloc((size_t)(NN + 1) * 4);
  int* cursor    = (int*)alloc((size_t)NN * 4);
  int2* sp       = (int2*)alloc((size_t)NE * 8);
  unsigned short* x_hi  = (unsigned short*)alloc((size_t)NN * 128 * 2);
  unsigned short* x_lo  = (unsigned short*)alloc((size_t)NN * 128 * 2);
  unsigned short* W1th  = (unsigned short*)alloc((size_t)512 * 128 * 2);
  unsigned short* W1tl  = (unsigned short*)alloc((size_t)512 * 128 * 2);
  unsigned short* W2th  = (unsigned short*)alloc((size_t)128 * 256 * 2);
  unsigned short* W2tl  = (unsigned short*)alloc((size_t)128 * 256 * 2);
  unsigned short* h_hi  = (unsigned short*)alloc((size_t)NN * 256 * 2);
  unsigned short* h_lo  = (unsigned short*)alloc((size_t)NN * 256 * 2);
  unsigned short* x1h   = (unsigned short*)alloc((size_t)NN * 512 * 2);
  unsigned short* x2h   = (unsigned short*)alloc((size_t)NN * 128 * 2);

  // CSR by destination (sp = (src, edge_id) pairs; no edge_attr copy)
  hipMemsetAsync(counts, 0, (size_t)NN * 4, stream);
  count_dst<<<(NE + 255) / 256, 256, 0, stream>>>(ei, counts);
  scan_local<<<(NN + 1023) / 1024, 1024, 0, stream>>>(counts, tmp, bsum);
  scan_bsum<<<1, 64, 0, stream>>>(bsum, (NN + 1023) / 1024);
  scan_finish<<<(NN + 255) / 256, 256, 0, stream>>>(counts, tmp, bsum, row_ptr, cursor);
  scatter_edges<<<(NE + 255) / 256, 256, 0, stream>>>(ei, cursor, sp);

  // split-bf16 conversions (W transposed for the B-resident GEMM)
  split_bf16<<<(NN * 128 + 255) / 256, 256, 0, stream>>>(x, x_hi, x_lo, NN * 128);
  cat_split_T<<<(512 * 128 + 255) / 256, 256, 0, stream>>>(Wl1, Wr1, W1th, W1tl, 256, 128,
                                                           512 * 128);
  cat_split_T<<<(128 * 256 + 255) / 256, 256, 0, stream>>>(Wl2, Wr2, W2th, W2tl, 64, 256,
                                                           128 * 256);

  // layer 1 (lo-plane store skipped: x1 is consumed hi-only by fused1)
  mfma_gemm_B<128, false><<<dim3((NN + 63) / 64, 8), 256, 0, stream>>>(
      x_hi, x_lo, W1th, W1tl, x1h, nullptr, NN, 512);
  fused1<<<NN, 64, 0, stream>>>(sp, row_ptr, eatt, x1h, We1, att1, b1, h_hi, h_lo);

  // layer 2 (lo-plane store skipped: x2 is consumed hi-only by fused2)
  mfma_gemm_B<256, false><<<dim3((NN + 63) / 64, 2), 256, 0, stream>>>(
      h_hi, h_lo, W2th, W2tl, x2h, nullptr, NN, 128);
  fused2<<<NN, 64, 0, stream>>>(sp, row_ptr, eatt, x2h, We2, att2, b2, out);
}

// Round 14
// 264.167 us; speedup vs baseline: 1.0520x; 1.0137x over previous
//
#include <hip/hip_runtime.h>

#define NN 20000
#define NE 320000

typedef __attribute__((ext_vector_type(8))) short bf16x8;
typedef __attribute__((ext_vector_type(4))) float f32x4;

__device__ __forceinline__ float bf2f(unsigned short u) {
  union { unsigned int i; float f; } v; v.i = ((unsigned int)u) << 16; return v.f;
}
__device__ __forceinline__ unsigned short f2bf(float f) {
  union { float f; unsigned int i; } v; v.f = f;
  unsigned int r = v.i + 0x7FFF + ((v.i >> 16) & 1);
  return (unsigned short)(r >> 16);
}
__device__ __forceinline__ float4 ld_bf4(const unsigned short* p) {
  ushort4 u = *(const ushort4*)p;
  float4 f;
  f.x = bf2f(u.x); f.y = bf2f(u.y); f.z = bf2f(u.z); f.w = bf2f(u.w);
  return f;
}

// 16-lane (DPP row) sum: 4 VALU adds, no LGKM. All 16 lanes end with the total.
__device__ __forceinline__ float rsum16(float v) {
  v += __int_as_float(__builtin_amdgcn_mov_dpp(__float_as_int(v), 0x121, 0xF, 0xF, true));
  v += __int_as_float(__builtin_amdgcn_mov_dpp(__float_as_int(v), 0x122, 0xF, 0xF, true));
  v += __int_as_float(__builtin_amdgcn_mov_dpp(__float_as_int(v), 0x124, 0xF, 0xF, true));
  v += __int_as_float(__builtin_amdgcn_mov_dpp(__float_as_int(v), 0x128, 0xF, 0xF, true));
  return v;
}

// ---------------- helpers (proven forms) ----------------

__device__ __forceinline__ void ea_fma(float4& v, const float4 ea, const float4* w) {
  v.x += ea.x * w[0].x + ea.y * w[1].x + ea.z * w[2].x + ea.w * w[3].x;
  v.y += ea.x * w[0].y + ea.y * w[1].y + ea.z * w[2].y + ea.w * w[3].y;
  v.z += ea.x * w[0].z + ea.y * w[1].z + ea.z * w[2].z + ea.w * w[3].z;
  v.w += ea.x * w[0].w + ea.y * w[1].w + ea.z * w[2].w + ea.w * w[3].w;
}

__device__ __forceinline__ void leaky4(float4& v) {
  v.x = (v.x > 0.f) ? v.x : 0.2f * v.x;
  v.y = (v.y > 0.f) ? v.y : 0.2f * v.y;
  v.z = (v.z > 0.f) ? v.z : 0.2f * v.z;
  v.w = (v.w > 0.f) ? v.w : 0.2f * v.w;
}

// ---------------- CSR construction ----------------

__global__ void count_dst(const int* __restrict__ ei, int* __restrict__ counts) {
  int e = blockIdx.x * blockDim.x + threadIdx.x;
  if (e < NE) atomicAdd(&counts[ei[NE + e]], 1);
}

__global__ void scan_local(const int* __restrict__ counts, int* __restrict__ tmp,
                           int* __restrict__ bsum) {
  __shared__ int sh[1024];
  int b = blockIdx.x, t = threadIdx.x, i = b * 1024 + t;
  int v = (i < NN) ? counts[i] : 0;
  sh[t] = v;
  __syncthreads();
  for (int off = 1; off < 1024; off <<= 1) {
    int add = (t >= off) ? sh[t - off] : 0;
    __syncthreads();
    sh[t] += add;
    __syncthreads();
  }
  if (i < NN) tmp[i] = sh[t];
  if (t == 1023) bsum[b] = sh[t];
}

// wave-parallel exclusive scan (round 11). Integer-exact.
__global__ void scan_bsum(int* __restrict__ bsum, int nb) {
  int lane = threadIdx.x;
  int v = (lane < nb) ? bsum[lane] : 0;
  for (int off = 1; off < 64; off <<= 1) {
    int t = __shfl_up(v, off);
    if (lane >= off) v += t;
  }
  int excl = __shfl_up(v, 1);
  if (lane == 0) excl = 0;
  if (lane < nb) bsum[lane] = excl;
}

__global__ void scan_finish(const int* __restrict__ counts, const int* __restrict__ tmp,
                            const int* __restrict__ bsum, int* __restrict__ row_ptr,
                            int* __restrict__ cursor) {
  int i = blockIdx.x * 256 + threadIdx.x;
  if (i == 0) row_ptr[0] = 0;
  if (i < NN) {
    int incl = tmp[i] + bsum[i >> 10];
    row_ptr[i + 1] = incl;
    cursor[i] = incl - counts[i];
  }
}

// round-12: scatter only (src, edge_id) as one 8-B store; consumers read the ORIGINAL
// edge_attr via the scalar-loaded edge id (no 20 MB reorder copy).
__global__ void scatter_edges(const int* __restrict__ ei, int* __restrict__ cursor,
                              int2* __restrict__ sp) {
  int e = blockIdx.x * blockDim.x + threadIdx.x;
  if (e < NE) {
    int d = ei[NE + e];
    int pos = atomicAdd(&cursor[d], 1);
    sp[pos] = make_int2(ei[e], e);
  }
}

// ---------------- split-bf16 conversion ----------------

__global__ void split_bf16(const float* __restrict__ src, unsigned short* __restrict__ hi,
                           unsigned short* __restrict__ lo, int n) {
  int i = blockIdx.x * 256 + threadIdx.x;
  if (i < n) {
    float v = src[i];
    unsigned short h = f2bf(v);
    hi[i] = h;
    lo[i] = f2bf(v - bf2f(h));
  }
}

__global__ void cat_split_T(const float* __restrict__ W1, const float* __restrict__ W2,
                            unsigned short* __restrict__ hi, unsigned short* __restrict__ lo,
                            int N0, int K, int total) {
  int i = blockIdx.x * 256 + threadIdx.x;
  if (i < total) {
    int n = i / K, k = i - n * K;
    float v = (n < N0) ? W1[k * N0 + n] : W2[k * N0 + n - N0];
    unsigned short h = f2bf(v);
    hi[i] = h;
    lo[i] = f2bf(v - bf2f(h));
  }
}

// ---------------- split-bf16 MFMA GEMM, B-resident-in-LDS, K-chunked staging ----------
// WLO=false skips the lo-plane C store (dead for x1/x2: fused kernels read hi only).
// round-13: B is staged in CK=128 chunks. For K=256 this cuts LDS 143->39 KB
// (1 -> 4 blocks/CU capacity; the old version ran at 1 wave/SIMD with zero latency
// hiding). Chunks iterate in ascending k with unchanged per-acc order -> bit-identical.

template<int K, bool WLO>
__global__ __launch_bounds__(256) void mfma_gemm_B(
    const unsigned short* __restrict__ Ah, const unsigned short* __restrict__ Al,
    const unsigned short* __restrict__ Bth, const unsigned short* __restrict__ Btl,
    unsigned short* __restrict__ Ch, unsigned short* __restrict__ Cl, int M, int N) {
  constexpr int CK = (K > 128) ? 128 : K;
  constexpr int BP = CK + 24;
  __shared__ unsigned short Bsh[64 * BP], Bsl[64 * BP];
  int t = threadIdx.x;
  int wv = t >> 6, lane = t & 63;
  int quad = lane >> 4, mrow = lane & 15;
  int m0 = blockIdx.x * 64;
  int n0 = blockIdx.y * 64;

  f32x4 acc[4];
#pragma unroll
  for (int i = 0; i < 4; ++i) acc[i] = (f32x4){0.f, 0.f, 0.f, 0.f};

  int arow = m0 + wv * 16 + mrow;
  if (arow >= M) arow = M - 1;
  const unsigned short* ap_h = Ah + (size_t)arow * K + quad * 8;
  const unsigned short* ap_l = Al + (size_t)arow * K + quad * 8;

  for (int kc = 0; kc < K; kc += CK) {
    for (int idx = t; idx < 64 * CK / 8; idx += 256) {
      int n = idx / (CK / 8), seg = (idx - n * (CK / 8)) * 8;
      *(uint4*)(Bsh + n * BP + seg) =
          *(const uint4*)(Bth + (size_t)(n0 + n) * K + kc + seg);
      *(uint4*)(Bsl + n * BP + seg) =
          *(const uint4*)(Btl + (size_t)(n0 + n) * K + kc + seg);
    }
    __syncthreads();

    for (int ks = 0; ks < CK; ks += 32) {
      bf16x8 ah = *(const bf16x8*)(ap_h + kc + ks);
      bf16x8 al = *(const bf16x8*)(ap_l + kc + ks);
#pragma unroll
      for (int nt = 0; nt < 4; ++nt) {
        bf16x8 bh = *(const bf16x8*)(Bsh + (nt * 16 + mrow) * BP + ks + quad * 8);
        bf16x8 bl = *(const bf16x8*)(Bsl + (nt * 16 + mrow) * BP + ks + quad * 8);
        acc[nt] = __builtin_amdgcn_mfma_f32_16x16x32_bf16(ah, bh, acc[nt], 0, 0, 0);
        acc[nt] = __builtin_amdgcn_mfma_f32_16x16x32_bf16(ah, bl, acc[nt], 0, 0, 0);
        acc[nt] = __builtin_amdgcn_mfma_f32_16x16x32_bf16(al, bh, acc[nt], 0, 0, 0);
      }
    }
    __syncthreads();
  }
#pragma unroll
  for (int nt = 0; nt < 4; ++nt)
#pragma unroll
    for (int r = 0; r < 4; ++r) {
      int row = m0 + wv * 16 + quad * 4 + r;
      if (row < M) {
        float f = acc[nt][r];
        unsigned short h = f2bf(f);
        size_t o = (size_t)row * N + n0 + nt * 16 + mrow;
        Ch[o] = h;
        if constexpr (WLO) Cl[o] = f2bf(f - bf2f(h));
      }
    }
}

// ---------------- FUSED layer 1 (round-12 state, byte-identical) ----------
// One wave per node (1-wave blocks), 2 edges/iter, scalar (src,edge) pairs s_loaded,
// ea read from the ORIGINAL edge_attr at the scalar edge-id base.
// CLOSED questions (all regressed): 4-wide (r3, r6), 2-waves/node (r4), manual
// prefetch pipeline (r8), packed v_pk_fma_f32 via inline asm (r0, r10).

__global__ __launch_bounds__(64, 1) void fused1(
    const int2* __restrict__ sp, const int* __restrict__ row_ptr,
    const float* __restrict__ eatt, const unsigned short* __restrict__ xh,
    const float* __restrict__ We, const float* __restrict__ att,
    const float* __restrict__ bias, unsigned short* __restrict__ h_hi,
    unsigned short* __restrict__ h_lo) {
  int lane = threadIdx.x & 63;
  int n = __builtin_amdgcn_readfirstlane(blockIdx.x);
  int col = (lane >> 4) * 64 + (lane & 15) * 4;
  float4 we[16];
#pragma unroll
  for (int k = 0; k < 16; ++k) we[k] = *(const float4*)(We + k * 256 + col);
  float4 at = *(const float4*)(att + col);
  float4 ra = ld_bf4(xh + (size_t)n * 512 + 256 + col);
  int beg = __builtin_amdgcn_readfirstlane(row_ptr[n]);
  int end = __builtin_amdgcn_readfirstlane(row_ptr[n + 1]);
  float den0 = 0.f, den1 = 0.f;
  float4 A0 = {0, 0, 0, 0}, A1 = {0, 0, 0, 0};
  int i = beg;
  for (; i + 2 <= end; i += 2) {
    int2 sp0 = sp[i], sp1 = sp[i + 1];
    int s0 = __builtin_amdgcn_readfirstlane(sp0.x);
    int e0 = __builtin_amdgcn_readfirstlane(sp0.y);
    int s1 = __builtin_amdgcn_readfirstlane(sp1.x);
    int e1 = __builtin_amdgcn_readfirstlane(sp1.y);
    float4 xa = ld_bf4(xh + (size_t)s0 * 512 + col);
    float4 xb = ld_bf4(xh + (size_t)s1 * 512 + col);
    const float4* ep0 = (const float4*)(eatt + (size_t)e0 * 16);
    const float4* ep1 = (const float4*)(eatt + (size_t)e1 * 16);
    float4 p0 = ep0[0], p1 = ep0[1], p2 = ep0[2], p3 = ep0[3];
    float4 q0 = ep1[0], q1 = ep1[1], q2 = ep1[2], q3 = ep1[3];
    float4 v0, v1;
    v0.x = xa.x + ra.x; v0.y = xa.y + ra.y; v0.z = xa.z + ra.z; v0.w = xa.w + ra.w;
    v1.x = xb.x + ra.x; v1.y = xb.y + ra.y; v1.z = xb.z + ra.z; v1.w = xb.w + ra.w;
    ea_fma(v0, p0, we + 0); ea_fma(v0, p1, we + 4);
    ea_fma(v0, p2, we + 8); ea_fma(v0, p3, we + 12);
    ea_fma(v1, q0, we + 0); ea_fma(v1, q1, we + 4);
    ea_fma(v1, q2, we + 8); ea_fma(v1, q3, we + 12);
    leaky4(v0); leaky4(v1);
    float sA = at.x * v0.x + at.y * v0.y + at.z * v0.z + at.w * v0.w;
    float sB = at.x * v1.x + at.y * v1.y + at.z * v1.z + at.w * v1.w;
    sA = rsum16(sA);
    sB = rsum16(sB);
    float pA = __expf(sA), pB = __expf(sB);
    den0 += pA; den1 += pB;
    A0.x += pA * xa.x; A0.y += pA * xa.y; A0.z += pA * xa.z; A0.w += pA * xa.w;
    A1.x += pB * xb.x; A1.y += pB * xb.y; A1.z += pB * xb.z; A1.w += pB * xb.w;
  }
  if (i < end) {  // tail edge
    int2 sp0 = sp[i];
    int s0 = __builtin_amdgcn_readfirstlane(sp0.x);
    int e0 = __builtin_amdgcn_readfirstlane(sp0.y);
    float4 xa = ld_bf4(xh + (size_t)s0 * 512 + col);
    const float4* ep0 = (const float4*)(eatt + (size_t)e0 * 16);
    float4 p0 = ep0[0], p1 = ep0[1], p2 = ep0[2], p3 = ep0[3];
    float4 v0;
    v0.x = xa.x + ra.x; v0.y = xa.y + ra.y; v0.z = xa.z + ra.z; v0.w = xa.w + ra.w;
    ea_fma(v0, p0, we + 0); ea_fma(v0, p1, we + 4);
    ea_fma(v0, p2, we + 8); ea_fma(v0, p3, we + 12);
    leaky4(v0);
    float sA = at.x * v0.x + at.y * v0.y + at.z * v0.z + at.w * v0.w;
    sA = rsum16(sA);
    float pA = __expf(sA);
    den0 += pA;
    A0.x += pA * xa.x; A0.y += pA * xa.y; A0.z += pA * xa.z; A0.w += pA * xa.w;
  }
  float D = den0 + den1;
  float4 A;
  A.x = A0.x + A1.x;
  A.y = A0.y + A1.y;
  A.z = A0.z + A1.z;
  A.w = A0.w + A1.w;
  bool has = end > beg;
  float rd = has ? 1.f / D : 0.f;
  float4 b4 = *(const float4*)(bias + col);
  float4 o;
  o.x = A.x * rd + b4.x;
  o.y = A.y * rd + b4.y;
  o.z = A.z * rd + b4.z;
  o.w = A.w * rd + b4.w;
  o.x = (o.x > 0.f) ? o.x : (__expf(o.x) - 1.f);
  o.y = (o.y > 0.f) ? o.y : (__expf(o.y) - 1.f);
  o.z = (o.z > 0.f) ? o.z : (__expf(o.z) - 1.f);
  o.w = (o.w > 0.f) ? o.w : (__expf(o.w) - 1.f);
  ushort4 oh, ol;
  oh.x = f2bf(o.x); ol.x = f2bf(o.x - bf2f(oh.x));
  oh.y = f2bf(o.y); ol.y = f2bf(o.y - bf2f(oh.y));
  oh.z = f2bf(o.z); ol.z = f2bf(o.z - bf2f(oh.z));
  oh.w = f2bf(o.w); ol.w = f2bf(o.w - bf2f(oh.w));
  *(ushort4*)(h_hi + (size_t)n * 256 + col) = oh;
  *(ushort4*)(h_lo + (size_t)n * 256 + col) = ol;
}

// ---------------- FUSED layer 2 (round-12 state, byte-identical) ----------

__global__ __launch_bounds__(64, 1) void fused2(
    const int2* __restrict__ sp, const int* __restrict__ row_ptr,
    const float* __restrict__ eatt, const unsigned short* __restrict__ xh,
    const float* __restrict__ We, const float* __restrict__ att,
    const float* __restrict__ bias, float* __restrict__ out) {
  int lane = threadIdx.x & 63;
  int n = __builtin_amdgcn_readfirstlane(blockIdx.x);
  float wcol[16];
#pragma unroll
  for (int k = 0; k < 16; ++k) wcol[k] = We[k * 64 + lane];
  float at = att[lane];
  float ra = bf2f(xh[(size_t)n * 128 + 64 + lane]);
  int beg = __builtin_amdgcn_readfirstlane(row_ptr[n]);
  int end = __builtin_amdgcn_readfirstlane(row_ptr[n + 1]);
  float den0 = 0.f, den1 = 0.f;
  float A0 = 0.f, A1 = 0.f;
  int i = beg;
  for (; i + 2 <= end; i += 2) {
    int2 sp0 = sp[i], sp1 = sp[i + 1];
    int s0 = __builtin_amdgcn_readfirstlane(sp0.x);
    int e0 = __builtin_amdgcn_readfirstlane(sp0.y);
    int s1 = __builtin_amdgcn_readfirstlane(sp1.x);
    int e1 = __builtin_amdgcn_readfirstlane(sp1.y);
    float xa0 = bf2f(xh[(size_t)s0 * 128 + lane]);
    float xa1 = bf2f(xh[(size_t)s1 * 128 + lane]);
    const float* ep0 = eatt + (size_t)e0 * 16;
    const float* ep1 = eatt + (size_t)e1 * 16;
    float v0 = xa0 + ra, v1 = xa1 + ra;
#pragma unroll
    for (int k = 0; k < 16; ++k) v0 += ep0[k] * wcol[k];
#pragma unroll
    for (int k = 0; k < 16; ++k) v1 += ep1[k] * wcol[k];
    v0 = fmaxf(v0, 0.2f * v0);
    v1 = fmaxf(v1, 0.2f * v1);
    float sA = at * v0, sB = at * v1;
    sA = rsum16(sA); sB = rsum16(sB);
    sA += __shfl_xor(sA, 16); sB += __shfl_xor(sB, 16);
    sA += __shfl_xor(sA, 32); sB += __shfl_xor(sB, 32);
    float pA = __expf(sA), pB = __expf(sB);
    den0 += pA; den1 += pB;
    A0 += pA * xa0; A1 += pB * xa1;
  }
  if (i < end) {  // tail edge
    int2 sp0 = sp[i];
    int s0 = __builtin_amdgcn_readfirstlane(sp0.x);
    int e0 = __builtin_amdgcn_readfirstlane(sp0.y);
    float xa0 = bf2f(xh[(size_t)s0 * 128 + lane]);
    const float* ep0 = eatt + (size_t)e0 * 16;
    float v0 = xa0 + ra;
#pragma unroll
    for (int k = 0; k < 16; ++k) v0 += ep0[k] * wcol[k];
    v0 = fmaxf(v0, 0.2f * v0);
    float sA = at * v0;
    sA = rsum16(sA);
    sA += __shfl_xor(sA, 16);
    sA += __shfl_xor(sA, 32);
    float pA = __expf(sA);
    den0 += pA;
    A0 += pA * xa0;
  }
  float D = den0 + den1;
  float A = A0 + A1;
  bool has = end > beg;
  float o = (has ? A / D : 0.f) + bias[lane];
  out[(size_t)n * 64 + lane] = o;
}

// ---------------- launch ----------------

extern "C" void kernel_launch(void* const* d_in, const int* in_sizes, int n_in,
                              void* d_out, int out_size, void* d_ws, size_t ws_size,
                              hipStream_t stream) {
  const float* x    = (const float*)d_in[0];
  const int*   ei   = (const int*)  d_in[1];
  const float* eatt = (const float*)d_in[2];
  const float* Wl1  = (const float*)d_in[3];
  const float* Wr1  = (const float*)d_in[4];
  const float* We1  = (const float*)d_in[5];
  const float* att1 = (const float*)d_in[6];
  const float* b1   = (const float*)d_in[7];
  const float* Wl2  = (const float*)d_in[8];
  const float* Wr2  = (const float*)d_in[9];
  const float* We2  = (const float*)d_in[10];
  const float* att2 = (const float*)d_in[11];
  const float* b2   = (const float*)d_in[12];
  float* out = (float*)d_out;

  char* wsb = (char*)d_ws;
  size_t off = 0;
  auto alloc = [&](size_t bytes) {
    char* p = wsb + off;
    off += (bytes + 255) & ~(size_t)255;
    return p;
  };
  int* counts    = (int*)alloc((size_t)NN * 4);
  int* tmp       = (int*)alloc((size_t)NN * 4);
  int* bsum      = (int*)alloc(32 * 4);
  int* row_ptr   = (int*)alloc((size_t)(NN + 1) * 4);
  int* cursor    = (int*)alloc((size_t)NN * 4);
  int2* sp       = (int2*)alloc((size_t)NE * 8);
  unsigned short* x_hi  = (unsigned short*)alloc((size_t)NN * 128 * 2);
  unsigned short* x_lo  = (unsigned short*)alloc((size_t)NN * 128 * 2);
  unsigned short* W1th  = (unsigned short*)alloc((size_t)512 * 128 * 2);
  unsigned short* W1tl  = (unsigned short*)alloc((size_t)512 * 128 * 2);
  unsigned short* W2th  = (unsigned short*)alloc((size_t)128 * 256 * 2);
  unsigned short* W2tl  = (unsigned short*)alloc((size_t)128 * 256 * 2);
  unsigned short* h_hi  = (unsigned short*)alloc((size_t)NN * 256 * 2);
  unsigned short* h_lo  = (unsigned short*)alloc((size_t)NN * 256 * 2);
  unsigned short* x1h   = (unsigned short*)alloc((size_t)NN * 512 * 2);
  unsigned short* x2h   = (unsigned short*)alloc((size_t)NN * 128 * 2);

  // CSR by destination (sp = (src, edge_id) pairs; no edge_attr copy)
  hipMemsetAsync(counts, 0, (size_t)NN * 4, stream);
  count_dst<<<(NE + 255) / 256, 256, 0, stream>>>(ei, counts);
  scan_local<<<(NN + 1023) / 1024, 1024, 0, stream>>>(counts, tmp, bsum);
  scan_bsum<<<1, 64, 0, stream>>>(bsum, (NN + 1023) / 1024);
  scan_finish<<<(NN + 255) / 256, 256, 0, stream>>>(counts, tmp, bsum, row_ptr, cursor);
  scatter_edges<<<(NE + 255) / 256, 256, 0, stream>>>(ei, cursor, sp);

  // split-bf16 conversions (W transposed for the B-resident GEMM)
  split_bf16<<<(NN * 128 + 255) / 256, 256, 0, stream>>>(x, x_hi, x_lo, NN * 128);
  cat_split_T<<<(512 * 128 + 255) / 256, 256, 0, stream>>>(Wl1, Wr1, W1th, W1tl, 256, 128,
                                                           512 * 128);
  cat_split_T<<<(128 * 256 + 255) / 256, 256, 0, stream>>>(Wl2, Wr2, W2th, W2tl, 64, 256,
                                                           128 * 256);

  // layer 1 (lo-plane store skipped: x1 is consumed hi-only by fused1)
  mfma_gemm_B<128, false><<<dim3((NN + 63) / 64, 8), 256, 0, stream>>>(
      x_hi, x_lo, W1th, W1tl, x1h, nullptr, NN, 512);
  fused1<<<NN, 64, 0, stream>>>(sp, row_ptr, eatt, x1h, We1, att1, b1, h_hi, h_lo);

  // layer 2 (lo-plane store skipped: x2 is consumed hi-only by fused2)
  mfma_gemm_B<256, false><<<dim3((NN + 63) / 64, 2), 256, 0, stream>>>(
      h_hi, h_lo, W2th, W2tl, x2h, nullptr, NN, 128);
  fused2<<<NN, 64, 0, stream>>>(sp, row_ptr, eatt, x2h, We2, att2, b2, out);
}